// Round 1
// baseline (667.334 us; speedup 1.0000x reference)
//
#include <hip/hip_runtime.h>

// LocalGlobalCausalSelfAttention — fp32 baseline (correctness-first).
//   out = ( softmax( mask( (xW_attn^T) split->Q,K,V ; QK^T/8 ) ) V ) W_proj^T
// Mask simplifies to: key j visible from query i  iff  j<=i && (j>=i-255 || j<4).
// Three kernels: SGEMM(x,w_attn)->qkv ; fused flash attention -> y ; SGEMM(y,w_proj)->out.
// Workspace: qkv (B*T*3C fp32 = 50.3MB) + y (B*T*C fp32 = 16.8MB) = 67.1MB in d_ws.

#define NHD   16
#define CEMB  1024
#define C3    3072
#define DH    64
#define WIN   256
#define NGLB  4
#define TB    256

// ===================== generic NT SGEMM: C[M,N] = A[M,K] * B[N,K]^T =====================
// 128x128 tile, BK=16, 256 threads, 8x8 micro-tile, LDS tiles stored transposed [k][m].
#define GM_BM 128
#define GM_BK 16
#define GM_LD (GM_BM + 4)   // pad 4 floats: keeps float4 alignment, breaks bank patterns

__global__ __launch_bounds__(TB)
void sgemm_nt_kernel(const float* __restrict__ A, const float* __restrict__ B,
                     float* __restrict__ C, int M, int N, int K) {
    __shared__ float As[GM_BK][GM_LD];
    __shared__ float Bs[GM_BK][GM_LD];

    const int tid = threadIdx.x;
    const int nbn = N / GM_BM;
    const int mb  = blockIdx.x / nbn;
    const int nb  = blockIdx.x % nbn;

    const float* Ab = A + (size_t)mb * GM_BM * K;
    const float* Bb = B + (size_t)nb * GM_BM * K;

    const int lrow = tid >> 2;        // 0..63 (second slot: +64)
    const int lk   = (tid & 3) << 2;  // 0,4,8,12

    const int r0 = (tid >> 4) << 3;   // 0..120
    const int c0 = (tid & 15) << 3;   // 0..120

    float acc[8][8];
#pragma unroll
    for (int i = 0; i < 8; ++i)
#pragma unroll
        for (int j = 0; j < 8; ++j) acc[i][j] = 0.f;

    for (int kt = 0; kt < K; kt += GM_BK) {
        float4 a0 = *(const float4*)(Ab + (size_t)lrow        * K + kt + lk);
        float4 a1 = *(const float4*)(Ab + (size_t)(lrow + 64) * K + kt + lk);
        float4 b0 = *(const float4*)(Bb + (size_t)lrow        * K + kt + lk);
        float4 b1 = *(const float4*)(Bb + (size_t)(lrow + 64) * K + kt + lk);
        __syncthreads();   // previous tile's compute finished
        As[lk + 0][lrow] = a0.x; As[lk + 1][lrow] = a0.y;
        As[lk + 2][lrow] = a0.z; As[lk + 3][lrow] = a0.w;
        As[lk + 0][lrow + 64] = a1.x; As[lk + 1][lrow + 64] = a1.y;
        As[lk + 2][lrow + 64] = a1.z; As[lk + 3][lrow + 64] = a1.w;
        Bs[lk + 0][lrow] = b0.x; Bs[lk + 1][lrow] = b0.y;
        Bs[lk + 2][lrow] = b0.z; Bs[lk + 3][lrow] = b0.w;
        Bs[lk + 0][lrow + 64] = b1.x; Bs[lk + 1][lrow + 64] = b1.y;
        Bs[lk + 2][lrow + 64] = b1.z; Bs[lk + 3][lrow + 64] = b1.w;
        __syncthreads();
#pragma unroll
        for (int k = 0; k < GM_BK; ++k) {
            float4 av0 = *(const float4*)&As[k][r0];
            float4 av1 = *(const float4*)&As[k][r0 + 4];
            float4 bv0 = *(const float4*)&Bs[k][c0];
            float4 bv1 = *(const float4*)&Bs[k][c0 + 4];
            float a[8] = {av0.x, av0.y, av0.z, av0.w, av1.x, av1.y, av1.z, av1.w};
            float b[8] = {bv0.x, bv0.y, bv0.z, bv0.w, bv1.x, bv1.y, bv1.z, bv1.w};
#pragma unroll
            for (int i = 0; i < 8; ++i)
#pragma unroll
                for (int j = 0; j < 8; ++j)
                    acc[i][j] = fmaf(a[i], b[j], acc[i][j]);
        }
    }

    float* Cb = C + (size_t)(mb * GM_BM + r0) * N + nb * GM_BM + c0;
#pragma unroll
    for (int i = 0; i < 8; ++i) {
        float4 o0 = {acc[i][0], acc[i][1], acc[i][2], acc[i][3]};
        float4 o1 = {acc[i][4], acc[i][5], acc[i][6], acc[i][7]};
        *(float4*)(Cb + (size_t)i * N)     = o0;
        *(float4*)(Cb + (size_t)i * N + 4) = o1;
    }
}

// ===================== fused local+global causal flash attention =====================
// One block per (b, h, 64-row q-tile). 64-key tiles. fp32 throughout.
// LDS layouts chosen so all compute-phase reads are row-wise (conflict-free):
//   Qst[d][i] (Q^T, pre-scaled by 1/8), Kst[d][j] (K^T), Vs[j][d], Pt[j][i] (P^T).
// Exactly 64KB static LDS -> 2 blocks/CU.
__global__ __launch_bounds__(TB)
void attn_kernel(const float* __restrict__ qkv, float* __restrict__ y,
                 int B, int T) {
    __shared__ float Qst[64][64];
    __shared__ float Kst[64][64];
    __shared__ float Vs [64][64];
    __shared__ float Pt [64][64];

    const int tid = threadIdx.x;
    const int nq  = T / 64;
    const int qt  = blockIdx.x % nq;
    const int bh  = blockIdx.x / nq;
    const int h   = bh % NHD;
    const int b   = bh / NHD;
    const int qs  = qt * 64;

    const size_t rs = C3;  // qkv row stride
    const float* qb = qkv + (size_t)b * T * rs + (size_t)h * DH;
    const float* kb = qb + CEMB;
    const float* vb = qb + 2 * CEMB;

    // ---- load Q tile, transposed + pre-scaled ----
#pragma unroll
    for (int p = 0; p < 4; ++p) {
        int s  = tid + p * TB;
        int i  = s >> 4;
        int d0 = (s & 15) << 2;
        float4 q = *(const float4*)(qb + (size_t)(qs + i) * rs + d0);
        Qst[d0 + 0][i] = q.x * 0.125f;
        Qst[d0 + 1][i] = q.y * 0.125f;
        Qst[d0 + 2][i] = q.z * 0.125f;
        Qst[d0 + 3][i] = q.w * 0.125f;
    }

    const int r0 = (tid >> 4) << 2;  // this thread's 4 q-rows (within tile)
    const int c0 = (tid & 15) << 2;  // this thread's 4 key-cols / d-cols

    float m[4], l[4], o[4][4];
#pragma unroll
    for (int i = 0; i < 4; ++i) {
        m[i] = -3.0e38f; l[i] = 0.f;
#pragma unroll
        for (int j = 0; j < 4; ++j) o[i][j] = 0.f;
    }

    // key-tile schedule: [global tile 0 if not already covered] + window tiles
    int kt_first = 0;
    int wstart = qs - (WIN - 1);
    if (wstart > 0) kt_first = wstart >> 6;
    const int has_g = (kt_first > 0) ? 1 : 0;
    const int npass = (qt - kt_first + 1) + has_g;

    for (int pass = 0; pass < npass; ++pass) {
        const int kt = (has_g && pass == 0) ? 0 : (kt_first + pass - has_g);
        const int k0 = kt * 64;

        // prefetch K,V tile to regs
        float4 kreg[4], vreg[4];
        int js[4], ds[4];
#pragma unroll
        for (int p = 0; p < 4; ++p) {
            int s  = tid + p * TB;
            js[p] = s >> 4;
            ds[p] = (s & 15) << 2;
            kreg[p] = *(const float4*)(kb + (size_t)(k0 + js[p]) * rs + ds[p]);
            vreg[p] = *(const float4*)(vb + (size_t)(k0 + js[p]) * rs + ds[p]);
        }
        __syncthreads();   // previous PV done reading Vs/Pt (and Q load visible, pass 0)
#pragma unroll
        for (int p = 0; p < 4; ++p) {
            Kst[ds[p] + 0][js[p]] = kreg[p].x;
            Kst[ds[p] + 1][js[p]] = kreg[p].y;
            Kst[ds[p] + 2][js[p]] = kreg[p].z;
            Kst[ds[p] + 3][js[p]] = kreg[p].w;
            *(float4*)&Vs[js[p]][ds[p]] = vreg[p];
        }
        __syncthreads();

        // ---- S = (Q/8) K^T ----
        float sv[4][4];
#pragma unroll
        for (int i = 0; i < 4; ++i)
#pragma unroll
            for (int j = 0; j < 4; ++j) sv[i][j] = 0.f;
#pragma unroll 8
        for (int d = 0; d < 64; ++d) {
            float4 qa = *(const float4*)&Qst[d][r0];
            float4 ka = *(const float4*)&Kst[d][c0];
            float a[4] = {qa.x, qa.y, qa.z, qa.w};
            float g[4] = {ka.x, ka.y, ka.z, ka.w};
#pragma unroll
            for (int i = 0; i < 4; ++i)
#pragma unroll
                for (int j = 0; j < 4; ++j)
                    sv[i][j] = fmaf(a[i], g[j], sv[i][j]);
        }

        // ---- mask + online softmax (16-lane groups share a row-set) ----
#pragma unroll
        for (int i = 0; i < 4; ++i) {
            const int qi  = qs + r0 + i;
            const int wlo = qi - (WIN - 1);
            float mx = m[i];
#pragma unroll
            for (int j = 0; j < 4; ++j) {
                int kj = k0 + c0 + j;
                bool valid = (kj <= qi) && ((kj >= wlo) || (kj < NGLB));
                sv[i][j] = valid ? sv[i][j] : -3.0e38f;
                mx = fmaxf(mx, sv[i][j]);
            }
#pragma unroll
            for (int off = 1; off < 16; off <<= 1)
                mx = fmaxf(mx, __shfl_xor(mx, off, 64));
            float alpha = __expf(m[i] - mx);     // -> 0 if m was -inf-ish; 1 if both
            float pv[4];
            float rs_ = 0.f;
#pragma unroll
            for (int j = 0; j < 4; ++j) {
                float p = (sv[i][j] > -1.0e38f) ? __expf(sv[i][j] - mx) : 0.f;
                pv[j] = p; rs_ += p;
            }
#pragma unroll
            for (int off = 1; off < 16; off <<= 1)
                rs_ += __shfl_xor(rs_, off, 64);
            l[i] = l[i] * alpha + rs_;
            m[i] = mx;
#pragma unroll
            for (int j = 0; j < 4; ++j) {
                o[i][j] *= alpha;
                Pt[c0 + j][r0 + i] = pv[j];      // transpose-write (16-way conflict, ~4% — baseline ok)
            }
        }
        __syncthreads();   // Pt visible

        // ---- O += P V ----
#pragma unroll 8
        for (int j = 0; j < 64; ++j) {
            float4 pa = *(const float4*)&Pt[j][r0];
            float4 va = *(const float4*)&Vs[j][c0];
            float a[4] = {pa.x, pa.y, pa.z, pa.w};
            float g[4] = {va.x, va.y, va.z, va.w};
#pragma unroll
            for (int i = 0; i < 4; ++i)
#pragma unroll
                for (int jj = 0; jj < 4; ++jj)
                    o[i][jj] = fmaf(a[i], g[jj], o[i][jj]);
        }
    }

    // ---- epilogue: normalize + write y[b, t, h*64 + d] ----
    float* yb = y + ((size_t)b * T + qs) * CEMB + (size_t)h * DH;
#pragma unroll
    for (int i = 0; i < 4; ++i) {
        float inv = 1.0f / l[i];
        float4 ov = {o[i][0] * inv, o[i][1] * inv, o[i][2] * inv, o[i][3] * inv};
        *(float4*)(yb + (size_t)(r0 + i) * CEMB + c0) = ov;
    }
}

// ===================== launcher =====================
extern "C" void kernel_launch(void* const* d_in, const int* in_sizes, int n_in,
                              void* d_out, int out_size, void* d_ws, size_t ws_size,
                              hipStream_t stream) {
    const float* x      = (const float*)d_in[0];
    const float* w_attn = (const float*)d_in[1];
    const float* w_proj = (const float*)d_in[2];
    float* out = (float*)d_out;

    const int T = 2048;
    const int B = in_sizes[0] / (T * CEMB);
    const int M = B * T;

    float* qkv = (float*)d_ws;                 // [M, 3C]
    float* yb  = qkv + (size_t)M * C3;         // [M, C]

    sgemm_nt_kernel<<<dim3((M / 128) * (C3 / 128)), dim3(TB), 0, stream>>>(
        x, w_attn, qkv, M, C3, CEMB);
    attn_kernel<<<dim3(B * NHD * (T / 64)), dim3(TB), 0, stream>>>(qkv, yb, B, T);
    sgemm_nt_kernel<<<dim3((M / 128) * (CEMB / 128)), dim3(TB), 0, stream>>>(
        yb, w_proj, out, M, CEMB, CEMB);
}

// Round 2
// 363.727 us; speedup vs baseline: 1.8347x; 1.8347x over previous
//
#include <hip/hip_runtime.h>

// LocalGlobalCausalSelfAttention — R2: GEMMs moved to 3-term split-bf16 MFMA.
//   C = Ah·Bh^T + Ah·Bl^T + Al·Bh^T   (each MFMA fp32-accumulated; ~2^-13 rel err)
// Attention kernel unchanged from R1 (fp32 flash-style) — MFMA-ized next round.
// Workspace: qkv f32 (50.3MB) + y f32 (16.8MB) + hi/lo bf16 planes (50.4MB) = 117.5MB.

#define NHD   16
#define CEMB  1024
#define C3    3072
#define DH    64
#define WIN   256
#define NGLB  4
#define TB    256

typedef __attribute__((ext_vector_type(8))) short short8v;
typedef __attribute__((ext_vector_type(4))) float  f32x4;
typedef __attribute__((ext_vector_type(8))) unsigned short ushort8v;

// ---------- fp32 -> (bf16 hi, bf16 lo) split, vectorized ----------
__device__ __forceinline__ unsigned short f2bf_rn(float f) {
    unsigned int u = __float_as_uint(f);
    u += 0x7fffu + ((u >> 16) & 1u);      // round-to-nearest-even
    return (unsigned short)(u >> 16);
}
__device__ __forceinline__ float bf2f(unsigned short h) {
    return __uint_as_float(((unsigned int)h) << 16);
}

__global__ __launch_bounds__(TB)
void split_bf16_kernel(const float* __restrict__ in, unsigned short* __restrict__ hi,
                       unsigned short* __restrict__ lo, int n8) {
    for (int i = blockIdx.x * blockDim.x + threadIdx.x; i < n8;
         i += gridDim.x * blockDim.x) {
        float4 v0 = ((const float4*)in)[2 * i];
        float4 v1 = ((const float4*)in)[2 * i + 1];
        float f[8] = {v0.x, v0.y, v0.z, v0.w, v1.x, v1.y, v1.z, v1.w};
        ushort8v h, l;
#pragma unroll
        for (int j = 0; j < 8; ++j) {
            unsigned short hb = f2bf_rn(f[j]);
            h[j] = hb;
            l[j] = f2bf_rn(f[j] - bf2f(hb));
        }
        *(ushort8v*)&hi[(size_t)i * 8] = h;
        *(ushort8v*)&lo[(size_t)i * 8] = l;
    }
}

// ---------- split-bf16 MFMA GEMM: C[M,N] = A[M,K] * B[N,K]^T ----------
// 128x128 tile, BK=32, 256 threads (4 waves, 2x2), wave tile 64x64 = 4x4 frags
// of mfma_f32_16x16x32_bf16. LDS: 4 planes (Ah,Al,Bh,Bl) of [128][32] bf16 = 32KB,
// staged via global_load_lds width-16 (linear LDS; swizzle is NULL at 2-phase).
__device__ __forceinline__ void g2l16(const void* g, void* l) {
    __builtin_amdgcn_global_load_lds(
        (const __attribute__((address_space(1))) void*)g,
        (__attribute__((address_space(3))) void*)l, 16, 0, 0);
}

__global__ __launch_bounds__(TB)
void gemm_split_mfma_kernel(const unsigned short* __restrict__ Ah,
                            const unsigned short* __restrict__ Al,
                            const unsigned short* __restrict__ Bh,
                            const unsigned short* __restrict__ Bl,
                            float* __restrict__ C, int M, int N, int K) {
    __shared__ unsigned short lds[4][128 * 32];   // Ah, Al, Bh, Bl planes

    const int tid  = threadIdx.x;
    const int wave = tid >> 6;
    const int lane = tid & 63;
    const int nbn  = N >> 7;
    const int mb   = blockIdx.x / nbn;
    const int nb   = blockIdx.x % nbn;

    // ---- staging geometry: call c in {0,1}: rows (c*4+wave)*16 + lane/4, k-slot lane&3
    const int row0 = (wave)     * 16 + (lane >> 2);        // c=0
    const int row1 = (wave + 4) * 16 + (lane >> 2);        // c=1
    const int koff = (lane & 3) * 8;
    const size_t aoff0 = (size_t)(mb * 128 + row0) * K + koff;
    const size_t aoff1 = (size_t)(mb * 128 + row1) * K + koff;
    const size_t boff0 = (size_t)(nb * 128 + row0) * K + koff;
    const size_t boff1 = (size_t)(nb * 128 + row1) * K + koff;
    // wave-uniform LDS bases (ushort index): (c*4+wave)*512
    const int l0 = wave * 512;
    const int l1 = (wave + 4) * 512;

    // ---- compute geometry
    const int wr = wave >> 1, wc = wave & 1;
    const int fr = lane & 15;            // frag row/col within 16
    const int ks = (lane >> 4) * 8;      // frag k-offset

    f32x4 acc[4][4];
#pragma unroll
    for (int m = 0; m < 4; ++m)
#pragma unroll
        for (int n = 0; n < 4; ++n) acc[m][n] = (f32x4){0.f, 0.f, 0.f, 0.f};

    for (int kt = 0; kt < K; kt += 32) {
        __syncthreads();                 // all waves done reading previous tile
        g2l16(Ah + aoff0 + kt, &lds[0][l0]);
        g2l16(Ah + aoff1 + kt, &lds[0][l1]);
        g2l16(Al + aoff0 + kt, &lds[1][l0]);
        g2l16(Al + aoff1 + kt, &lds[1][l1]);
        g2l16(Bh + boff0 + kt, &lds[2][l0]);
        g2l16(Bh + boff1 + kt, &lds[2][l1]);
        g2l16(Bl + boff0 + kt, &lds[3][l0]);
        g2l16(Bl + boff1 + kt, &lds[3][l1]);
        __syncthreads();                 // vmcnt(0) drain -> staged data visible

        short8v ah[4], al[4], bh[4], bl[4];
#pragma unroll
        for (int m = 0; m < 4; ++m) {
            const int r = (wr * 64 + m * 16 + fr) * 32 + ks;
            ah[m] = *(const short8v*)&lds[0][r];
            al[m] = *(const short8v*)&lds[1][r];
        }
#pragma unroll
        for (int n = 0; n < 4; ++n) {
            const int r = (wc * 64 + n * 16 + fr) * 32 + ks;
            bh[n] = *(const short8v*)&lds[2][r];
            bl[n] = *(const short8v*)&lds[3][r];
        }
#pragma unroll
        for (int m = 0; m < 4; ++m)
#pragma unroll
            for (int n = 0; n < 4; ++n) {
                acc[m][n] = __builtin_amdgcn_mfma_f32_16x16x32_bf16(
                    ah[m], bh[n], acc[m][n], 0, 0, 0);
                acc[m][n] = __builtin_amdgcn_mfma_f32_16x16x32_bf16(
                    ah[m], bl[n], acc[m][n], 0, 0, 0);
                acc[m][n] = __builtin_amdgcn_mfma_f32_16x16x32_bf16(
                    al[m], bh[n], acc[m][n], 0, 0, 0);
            }
    }

    // ---- C write: frag C/D mapping col = lane&15, row = (lane>>4)*4 + reg
    const int cr = (lane >> 4) * 4;
    float* Cb = C + (size_t)(mb * 128 + wr * 64) * N + nb * 128 + wc * 64;
#pragma unroll
    for (int m = 0; m < 4; ++m)
#pragma unroll
        for (int n = 0; n < 4; ++n) {
#pragma unroll
            for (int r = 0; r < 4; ++r)
                Cb[(size_t)(m * 16 + cr + r) * N + n * 16 + fr] = acc[m][n][r];
        }
}

// ===================== fused local+global causal flash attention (unchanged R1) =====================
__global__ __launch_bounds__(TB)
void attn_kernel(const float* __restrict__ qkv, float* __restrict__ y,
                 int B, int T) {
    __shared__ float Qst[64][64];
    __shared__ float Kst[64][64];
    __shared__ float Vs [64][64];
    __shared__ float Pt [64][64];

    const int tid = threadIdx.x;
    const int nq  = T / 64;
    const int qt  = blockIdx.x % nq;
    const int bh  = blockIdx.x / nq;
    const int h   = bh % NHD;
    const int b   = bh / NHD;
    const int qs  = qt * 64;

    const size_t rs = C3;
    const float* qb = qkv + (size_t)b * T * rs + (size_t)h * DH;
    const float* kb = qb + CEMB;
    const float* vb = qb + 2 * CEMB;

#pragma unroll
    for (int p = 0; p < 4; ++p) {
        int s  = tid + p * TB;
        int i  = s >> 4;
        int d0 = (s & 15) << 2;
        float4 q = *(const float4*)(qb + (size_t)(qs + i) * rs + d0);
        Qst[d0 + 0][i] = q.x * 0.125f;
        Qst[d0 + 1][i] = q.y * 0.125f;
        Qst[d0 + 2][i] = q.z * 0.125f;
        Qst[d0 + 3][i] = q.w * 0.125f;
    }

    const int r0 = (tid >> 4) << 2;
    const int c0 = (tid & 15) << 2;

    float m[4], l[4], o[4][4];
#pragma unroll
    for (int i = 0; i < 4; ++i) {
        m[i] = -3.0e38f; l[i] = 0.f;
#pragma unroll
        for (int j = 0; j < 4; ++j) o[i][j] = 0.f;
    }

    int kt_first = 0;
    int wstart = qs - (WIN - 1);
    if (wstart > 0) kt_first = wstart >> 6;
    const int has_g = (kt_first > 0) ? 1 : 0;
    const int npass = (qt - kt_first + 1) + has_g;

    for (int pass = 0; pass < npass; ++pass) {
        const int kt = (has_g && pass == 0) ? 0 : (kt_first + pass - has_g);
        const int k0 = kt * 64;

        float4 kreg[4], vreg[4];
        int js[4], ds[4];
#pragma unroll
        for (int p = 0; p < 4; ++p) {
            int s  = tid + p * TB;
            js[p] = s >> 4;
            ds[p] = (s & 15) << 2;
            kreg[p] = *(const float4*)(kb + (size_t)(k0 + js[p]) * rs + ds[p]);
            vreg[p] = *(const float4*)(vb + (size_t)(k0 + js[p]) * rs + ds[p]);
        }
        __syncthreads();
#pragma unroll
        for (int p = 0; p < 4; ++p) {
            Kst[ds[p] + 0][js[p]] = kreg[p].x;
            Kst[ds[p] + 1][js[p]] = kreg[p].y;
            Kst[ds[p] + 2][js[p]] = kreg[p].z;
            Kst[ds[p] + 3][js[p]] = kreg[p].w;
            *(float4*)&Vs[js[p]][ds[p]] = vreg[p];
        }
        __syncthreads();

        float sv[4][4];
#pragma unroll
        for (int i = 0; i < 4; ++i)
#pragma unroll
            for (int j = 0; j < 4; ++j) sv[i][j] = 0.f;
#pragma unroll 8
        for (int d = 0; d < 64; ++d) {
            float4 qa = *(const float4*)&Qst[d][r0];
            float4 ka = *(const float4*)&Kst[d][c0];
            float a[4] = {qa.x, qa.y, qa.z, qa.w};
            float g[4] = {ka.x, ka.y, ka.z, ka.w};
#pragma unroll
            for (int i = 0; i < 4; ++i)
#pragma unroll
                for (int j = 0; j < 4; ++j)
                    sv[i][j] = fmaf(a[i], g[j], sv[i][j]);
        }

#pragma unroll
        for (int i = 0; i < 4; ++i) {
            const int qi  = qs + r0 + i;
            const int wlo = qi - (WIN - 1);
            float mx = m[i];
#pragma unroll
            for (int j = 0; j < 4; ++j) {
                int kj = k0 + c0 + j;
                bool valid = (kj <= qi) && ((kj >= wlo) || (kj < NGLB));
                sv[i][j] = valid ? sv[i][j] : -3.0e38f;
                mx = fmaxf(mx, sv[i][j]);
            }
#pragma unroll
            for (int off = 1; off < 16; off <<= 1)
                mx = fmaxf(mx, __shfl_xor(mx, off, 64));
            float alpha = __expf(m[i] - mx);
            float pv[4];
            float rs_ = 0.f;
#pragma unroll
            for (int j = 0; j < 4; ++j) {
                float p = (sv[i][j] > -1.0e38f) ? __expf(sv[i][j] - mx) : 0.f;
                pv[j] = p; rs_ += p;
            }
#pragma unroll
            for (int off = 1; off < 16; off <<= 1)
                rs_ += __shfl_xor(rs_, off, 64);
            l[i] = l[i] * alpha + rs_;
            m[i] = mx;
#pragma unroll
            for (int j = 0; j < 4; ++j) {
                o[i][j] *= alpha;
                Pt[c0 + j][r0 + i] = pv[j];
            }
        }
        __syncthreads();

#pragma unroll 8
        for (int j = 0; j < 64; ++j) {
            float4 pa = *(const float4*)&Pt[j][r0];
            float4 va = *(const float4*)&Vs[j][c0];
            float a[4] = {pa.x, pa.y, pa.z, pa.w};
            float g[4] = {va.x, va.y, va.z, va.w};
#pragma unroll
            for (int i = 0; i < 4; ++i)
#pragma unroll
                for (int jj = 0; jj < 4; ++jj)
                    o[i][jj] = fmaf(a[i], g[jj], o[i][jj]);
        }
    }

    float* yb = y + ((size_t)b * T + qs) * CEMB + (size_t)h * DH;
#pragma unroll
    for (int i = 0; i < 4; ++i) {
        float inv = 1.0f / l[i];
        float4 ov = {o[i][0] * inv, o[i][1] * inv, o[i][2] * inv, o[i][3] * inv};
        *(float4*)(yb + (size_t)(r0 + i) * CEMB + c0) = ov;
    }
}

// ===================== launcher =====================
extern "C" void kernel_launch(void* const* d_in, const int* in_sizes, int n_in,
                              void* d_out, int out_size, void* d_ws, size_t ws_size,
                              hipStream_t stream) {
    const float* x      = (const float*)d_in[0];
    const float* w_attn = (const float*)d_in[1];
    const float* w_proj = (const float*)d_in[2];
    float* out = (float*)d_out;

    const int T = 2048;
    const int B = in_sizes[0] / (T * CEMB);
    const int M = B * T;

    float* qkv = (float*)d_ws;                       // [M, 3C] f32
    float* yb  = qkv + (size_t)M * C3;               // [M, C]  f32
    unsigned short* xh  = (unsigned short*)(yb + (size_t)M * CEMB);
    unsigned short* xl  = xh  + (size_t)M * CEMB;
    unsigned short* wah = xl  + (size_t)M * CEMB;
    unsigned short* wal = wah + (size_t)C3 * CEMB;
    unsigned short* wph = wal + (size_t)C3 * CEMB;
    unsigned short* wpl = wph + (size_t)CEMB * CEMB;
    unsigned short* yh  = wpl + (size_t)CEMB * CEMB;
    unsigned short* yl  = yh  + (size_t)M * CEMB;

    split_bf16_kernel<<<2048, TB, 0, stream>>>(x, xh, xl, M * CEMB / 8);
    split_bf16_kernel<<<1536, TB, 0, stream>>>(w_attn, wah, wal, C3 * CEMB / 8);
    split_bf16_kernel<<<512,  TB, 0, stream>>>(w_proj, wph, wpl, CEMB * CEMB / 8);

    gemm_split_mfma_kernel<<<dim3((M / 128) * (C3 / 128)), dim3(TB), 0, stream>>>(
        xh, xl, wah, wal, qkv, M, C3, CEMB);

    attn_kernel<<<dim3(B * NHD * (T / 64)), dim3(TB), 0, stream>>>(qkv, yb, B, T);

    split_bf16_kernel<<<2048, TB, 0, stream>>>(yb, yh, yl, M * CEMB / 8);

    gemm_split_mfma_kernel<<<dim3((M / 128) * (CEMB / 128)), dim3(TB), 0, stream>>>(
        yh, yl, wph, wpl, out, M, CEMB, CEMB);
}

// Round 5
// 278.579 us; speedup vs baseline: 2.3955x; 1.3056x over previous
//
#include <hip/hip_runtime.h>

// LocalGlobalCausalSelfAttention — R3 resubmit #2 (R3/R4 benches were infra
// failures — acquisition timeout / container loss — not kernel verdicts;
// code unchanged for a clean measurement).
// Pipeline: split(x,w_attn,w_proj) -> GEMM1 (emits qkv as hi/lo bf16, Q pre-scaled 1/8)
//           -> attn (MFMA QK^T + PV, 3-term split, emits y as hi/lo bf16)
//           -> GEMM2 (f32 out).
// All LDS tiles XOR-swizzled; K/V reg-staged one tile ahead (async-stage).

#define NHD   16
#define CEMB  1024
#define C3    3072
#define DH    64
#define WIN   256
#define NGLB  4
#define TB    256

typedef __attribute__((ext_vector_type(8))) short  short8v;
typedef __attribute__((ext_vector_type(4))) float  f32x4;
typedef __attribute__((ext_vector_type(8))) unsigned short ushort8v;

__device__ __forceinline__ unsigned short f2bf_rn(float f) {
    unsigned int u = __float_as_uint(f);
    u += 0x7fffu + ((u >> 16) & 1u);
    return (unsigned short)(u >> 16);
}
__device__ __forceinline__ float bf2f(unsigned short h) {
    return __uint_as_float(((unsigned int)h) << 16);
}

__global__ __launch_bounds__(TB)
void split_bf16_kernel(const float* __restrict__ in, unsigned short* __restrict__ hi,
                       unsigned short* __restrict__ lo, int n8) {
    for (int i = blockIdx.x * blockDim.x + threadIdx.x; i < n8;
         i += gridDim.x * blockDim.x) {
        float4 v0 = ((const float4*)in)[2 * i];
        float4 v1 = ((const float4*)in)[2 * i + 1];
        float f[8] = {v0.x, v0.y, v0.z, v0.w, v1.x, v1.y, v1.z, v1.w};
        ushort8v h, l;
#pragma unroll
        for (int j = 0; j < 8; ++j) {
            unsigned short hb = f2bf_rn(f[j]);
            h[j] = hb;
            l[j] = f2bf_rn(f[j] - bf2f(hb));
        }
        *(ushort8v*)&hi[(size_t)i * 8] = h;
        *(ushort8v*)&lo[(size_t)i * 8] = l;
    }
}

// ---------- split-bf16 MFMA GEMM: C[M,N] = A[M,K] * B[N,K]^T ----------
__device__ __forceinline__ void g2l16(const void* g, void* l) {
    __builtin_amdgcn_global_load_lds(
        (const __attribute__((address_space(1))) void*)g,
        (__attribute__((address_space(3))) void*)l, 16, 0, 0);
}

// OUTMODE 0: f32 C.  OUTMODE 1: hi/lo bf16 C, cols < CEMB scaled by 1/8 (Q).
template<int OUTMODE>
__global__ __launch_bounds__(TB)
void gemm_split_mfma_kernel(const unsigned short* __restrict__ Ah,
                            const unsigned short* __restrict__ Al,
                            const unsigned short* __restrict__ Bh,
                            const unsigned short* __restrict__ Bl,
                            float* __restrict__ Cf,
                            unsigned short* __restrict__ Ch,
                            unsigned short* __restrict__ Cl,
                            int M, int N, int K) {
    __shared__ unsigned short lds[4][128 * 32];

    const int tid  = threadIdx.x;
    const int wave = tid >> 6;
    const int lane = tid & 63;
    const int nbn  = N >> 7;
    const int mb   = blockIdx.x / nbn;
    const int nb   = blockIdx.x % nbn;

    const int row0 = (wave)     * 16 + (lane >> 2);
    const int row1 = (wave + 4) * 16 + (lane >> 2);
    const int koff = (lane & 3) * 8;
    const size_t aoff0 = (size_t)(mb * 128 + row0) * K + koff;
    const size_t aoff1 = (size_t)(mb * 128 + row1) * K + koff;
    const size_t boff0 = (size_t)(nb * 128 + row0) * K + koff;
    const size_t boff1 = (size_t)(nb * 128 + row1) * K + koff;
    const int l0 = wave * 512;
    const int l1 = (wave + 4) * 512;

    const int wr = wave >> 1, wc = wave & 1;
    const int fr = lane & 15;
    const int ks = (lane >> 4) * 8;

    f32x4 acc[4][4];
#pragma unroll
    for (int m = 0; m < 4; ++m)
#pragma unroll
        for (int n = 0; n < 4; ++n) acc[m][n] = (f32x4){0.f, 0.f, 0.f, 0.f};

    for (int kt = 0; kt < K; kt += 32) {
        __syncthreads();
        g2l16(Ah + aoff0 + kt, &lds[0][l0]);
        g2l16(Ah + aoff1 + kt, &lds[0][l1]);
        g2l16(Al + aoff0 + kt, &lds[1][l0]);
        g2l16(Al + aoff1 + kt, &lds[1][l1]);
        g2l16(Bh + boff0 + kt, &lds[2][l0]);
        g2l16(Bh + boff1 + kt, &lds[2][l1]);
        g2l16(Bl + boff0 + kt, &lds[3][l0]);
        g2l16(Bl + boff1 + kt, &lds[3][l1]);
        __syncthreads();

        short8v ah[4], al[4], bh[4], bl[4];
#pragma unroll
        for (int m = 0; m < 4; ++m) {
            const int r = (wr * 64 + m * 16 + fr) * 32 + ks;
            ah[m] = *(const short8v*)&lds[0][r];
            al[m] = *(const short8v*)&lds[1][r];
        }
#pragma unroll
        for (int n = 0; n < 4; ++n) {
            const int r = (wc * 64 + n * 16 + fr) * 32 + ks;
            bh[n] = *(const short8v*)&lds[2][r];
            bl[n] = *(const short8v*)&lds[3][r];
        }
#pragma unroll
        for (int m = 0; m < 4; ++m)
#pragma unroll
            for (int n = 0; n < 4; ++n) {
                acc[m][n] = __builtin_amdgcn_mfma_f32_16x16x32_bf16(
                    ah[m], bh[n], acc[m][n], 0, 0, 0);
                acc[m][n] = __builtin_amdgcn_mfma_f32_16x16x32_bf16(
                    ah[m], bl[n], acc[m][n], 0, 0, 0);
                acc[m][n] = __builtin_amdgcn_mfma_f32_16x16x32_bf16(
                    al[m], bh[n], acc[m][n], 0, 0, 0);
            }
    }

    const int cr = (lane >> 4) * 4;
#pragma unroll
    for (int m = 0; m < 4; ++m)
#pragma unroll
        for (int n = 0; n < 4; ++n) {
#pragma unroll
            for (int r = 0; r < 4; ++r) {
                const int row = mb * 128 + wr * 64 + m * 16 + cr + r;
                const int col = nb * 128 + wc * 64 + n * 16 + fr;
                if constexpr (OUTMODE == 0) {
                    Cf[(size_t)row * N + col] = acc[m][n][r];
                } else {
                    float v = acc[m][n][r];
                    if (col < CEMB) v *= 0.125f;   // pre-scale Q by 1/sqrt(D)
                    unsigned short hb = f2bf_rn(v);
                    Ch[(size_t)row * N + col] = hb;
                    Cl[(size_t)row * N + col] = f2bf_rn(v - bf2f(hb));
                }
            }
        }
}

// ---------- fused attention, split-bf16 MFMA ----------
// Block = (b, h, 64-row q-tile), 4 waves; wave w owns q rows [w*16, w*16+16).
// LDS (all [64][64] bf16, XOR-swizzled on ushort index):
//   Kh/Kl  [key][d]   idx = key*64 + (off ^ ((key&7)<<3))
//   VTh/VTl[d][key]   idx = d*64   + (key ^ (((d^(d>>3))&7)<<3))
//   Ph/Pl  [q][key]   idx = q*64   + (key ^ ((q&7)<<3))    (wave-local roundtrip)
__global__ __launch_bounds__(TB)
void attn_mfma_kernel(const unsigned short* __restrict__ qkvh,
                      const unsigned short* __restrict__ qkvl,
                      unsigned short* __restrict__ yh,
                      unsigned short* __restrict__ yl, int T) {
    __shared__ unsigned short Kh[4096], Kl[4096], VTh[4096], VTl[4096],
                              Ph[4096], Pl[4096];

    const int tid = threadIdx.x;
    const int wv  = tid >> 6, ln = tid & 63;
    const int g   = ln >> 4, fr = ln & 15;
    const int nq  = T >> 6;
    const int qt  = blockIdx.x % nq;
    const int bh  = blockIdx.x / nq;
    const int h   = bh % NHD, b = bh / NHD;
    const int qs  = qt << 6;
    const size_t bT = (size_t)b * T;

    // Q A-frags straight from global (Q pre-scaled by 1/8 in GEMM1)
    const size_t qbase = (bT + qs + wv * 16 + fr) * C3 + h * DH;
    short8v qfh[2], qfl[2];
    qfh[0] = *(const short8v*)(qkvh + qbase + g * 8);
    qfh[1] = *(const short8v*)(qkvh + qbase + 32 + g * 8);
    qfl[0] = *(const short8v*)(qkvl + qbase + g * 8);
    qfl[1] = *(const short8v*)(qkvl + qbase + 32 + g * 8);

    float mrow[4], lrow[4];
    f32x4 acc_o[4];
#pragma unroll
    for (int r = 0; r < 4; ++r) { mrow[r] = -3.0e38f; lrow[r] = 0.f; }
#pragma unroll
    for (int j = 0; j < 4; ++j) acc_o[j] = (f32x4){0.f, 0.f, 0.f, 0.f};

    int kt_first = 0;
    const int wstart = qs - (WIN - 1);
    if (wstart > 0) kt_first = wstart >> 6;
    const int has_g = (kt_first > 0) ? 1 : 0;
    const int npass = qt - kt_first + 1 + has_g;

    // staging geometry: thread -> (row=tid>>2, chunk sc=tid&3)
    const int srow = tid >> 2;
    const int sc   = tid & 3;
    const int kidx0 = srow * 64 + ((sc * 8)       ^ ((srow & 7) << 3));
    const int kidx1 = srow * 64 + (((sc + 4) * 8) ^ ((srow & 7) << 3));

    short8v kh0, kh1, kl0, kl1, vh0, vh1, vl0, vl1;
    auto load_tile = [&](int k0) {
        const size_t kb = (bT + k0 + srow) * C3 + CEMB + h * DH;
        kh0 = *(const short8v*)(qkvh + kb + sc * 8);
        kh1 = *(const short8v*)(qkvh + kb + (sc + 4) * 8);
        kl0 = *(const short8v*)(qkvl + kb + sc * 8);
        kl1 = *(const short8v*)(qkvl + kb + (sc + 4) * 8);
        const size_t vb = (bT + k0 + srow) * C3 + 2 * CEMB + h * DH + sc * 16;
        vh0 = *(const short8v*)(qkvh + vb);
        vh1 = *(const short8v*)(qkvh + vb + 8);
        vl0 = *(const short8v*)(qkvl + vb);
        vl1 = *(const short8v*)(qkvl + vb + 8);
    };
    auto kt_of = [&](int p) { return (has_g && p == 0) ? 0 : (kt_first + p - has_g); };

    load_tile(kt_of(0) * 64);

    for (int pass = 0; pass < npass; ++pass) {
        const int k0 = kt_of(pass) * 64;

        __syncthreads();                    // prev tile compute done
        *(short8v*)&Kh[kidx0] = kh0; *(short8v*)&Kh[kidx1] = kh1;
        *(short8v*)&Kl[kidx0] = kl0; *(short8v*)&Kl[kidx1] = kl1;
#pragma unroll
        for (int e = 0; e < 8; ++e) {
            const int d1 = sc * 16 + e, d2 = sc * 16 + 8 + e;
            const int i1 = d1 * 64 + (srow ^ (((d1 ^ (d1 >> 3)) & 7) << 3));
            const int i2 = d2 * 64 + (srow ^ (((d2 ^ (d2 >> 3)) & 7) << 3));
            VTh[i1] = (unsigned short)vh0[e]; VTh[i2] = (unsigned short)vh1[e];
            VTl[i1] = (unsigned short)vl0[e]; VTl[i2] = (unsigned short)vl1[e];
        }
        __syncthreads();                    // staging visible

        if (pass + 1 < npass) load_tile(kt_of(pass + 1) * 64);  // overlaps compute

        // ---- S = Q K^T (3-term split) ----
        f32x4 sa[4];
#pragma unroll
        for (int j = 0; j < 4; ++j) sa[j] = (f32x4){0.f, 0.f, 0.f, 0.f};
#pragma unroll
        for (int kk = 0; kk < 2; ++kk) {
#pragma unroll
            for (int j = 0; j < 4; ++j) {
                const int krow = j * 16 + fr;
                const int off  = (kk * 32 + g * 8) ^ ((krow & 7) << 3);
                short8v bhf = *(const short8v*)&Kh[krow * 64 + off];
                short8v blf = *(const short8v*)&Kl[krow * 64 + off];
                sa[j] = __builtin_amdgcn_mfma_f32_16x16x32_bf16(qfh[kk], bhf, sa[j], 0, 0, 0);
                sa[j] = __builtin_amdgcn_mfma_f32_16x16x32_bf16(qfh[kk], blf, sa[j], 0, 0, 0);
                sa[j] = __builtin_amdgcn_mfma_f32_16x16x32_bf16(qfl[kk], bhf, sa[j], 0, 0, 0);
            }
        }

        // ---- mask + online softmax + P hi/lo to LDS (wave-local) ----
#pragma unroll
        for (int r = 0; r < 4; ++r) {
            const int qloc = wv * 16 + g * 4 + r;
            const int qi   = qs + qloc;
            const int wlo  = qi - (WIN - 1);
            float mx = mrow[r];
            float s[4];
#pragma unroll
            for (int j = 0; j < 4; ++j) {
                const int kj = k0 + j * 16 + fr;
                const bool valid = (kj <= qi) && ((kj >= wlo) || (kj < NGLB));
                s[j] = valid ? sa[j][r] : -3.0e38f;
                mx = fmaxf(mx, s[j]);
            }
#pragma unroll
            for (int off = 1; off < 16; off <<= 1)
                mx = fmaxf(mx, __shfl_xor(mx, off, 64));
            const float alpha = __expf(mrow[r] - mx);
            float rsum = 0.f;
            unsigned short phv[4], plv[4];
#pragma unroll
            for (int j = 0; j < 4; ++j) {
                const float p = (s[j] > -1.0e38f) ? __expf(s[j] - mx) : 0.f;
                rsum += p;
                const unsigned short hb = f2bf_rn(p);
                phv[j] = hb; plv[j] = f2bf_rn(p - bf2f(hb));
            }
#pragma unroll
            for (int off = 1; off < 16; off <<= 1)
                rsum += __shfl_xor(rsum, off, 64);
            lrow[r] = lrow[r] * alpha + rsum;
            mrow[r] = mx;
#pragma unroll
            for (int j = 0; j < 4; ++j) {
                acc_o[j][r] *= alpha;
                const int key = j * 16 + fr;
                const int idx = qloc * 64 + (key ^ ((qloc & 7) << 3));
                Ph[idx] = phv[j]; Pl[idx] = plv[j];
            }
        }

        // ---- O += P V (3-term split); P roundtrip is wave-local (no barrier) ----
#pragma unroll
        for (int kk = 0; kk < 2; ++kk) {
            const int qloc = wv * 16 + fr;
            const int poff = (kk * 32 + g * 8) ^ ((qloc & 7) << 3);
            short8v pah = *(const short8v*)&Ph[qloc * 64 + poff];
            short8v pal = *(const short8v*)&Pl[qloc * 64 + poff];
#pragma unroll
            for (int j = 0; j < 4; ++j) {
                const int d   = j * 16 + fr;
                const int voff = (kk * 32 + g * 8) ^ (((d ^ (d >> 3)) & 7) << 3);
                short8v vfh = *(const short8v*)&VTh[d * 64 + voff];
                short8v vfl = *(const short8v*)&VTl[d * 64 + voff];
                acc_o[j] = __builtin_amdgcn_mfma_f32_16x16x32_bf16(pah, vfh, acc_o[j], 0, 0, 0);
                acc_o[j] = __builtin_amdgcn_mfma_f32_16x16x32_bf16(pah, vfl, acc_o[j], 0, 0, 0);
                acc_o[j] = __builtin_amdgcn_mfma_f32_16x16x32_bf16(pal, vfh, acc_o[j], 0, 0, 0);
            }
        }
    }

    // ---- epilogue: normalize, split hi/lo, write y ----
    float inv[4];
#pragma unroll
    for (int r = 0; r < 4; ++r) inv[r] = 1.0f / lrow[r];
#pragma unroll
    for (int j = 0; j < 4; ++j)
#pragma unroll
        for (int r = 0; r < 4; ++r) {
            const float o = acc_o[j][r] * inv[r];
            const size_t yi = (bT + qs + wv * 16 + g * 4 + r) * (size_t)CEMB
                            + h * DH + j * 16 + fr;
            const unsigned short hb = f2bf_rn(o);
            yh[yi] = hb; yl[yi] = f2bf_rn(o - bf2f(hb));
        }
}

// ===================== launcher =====================
extern "C" void kernel_launch(void* const* d_in, const int* in_sizes, int n_in,
                              void* d_out, int out_size, void* d_ws, size_t ws_size,
                              hipStream_t stream) {
    const float* x      = (const float*)d_in[0];
    const float* w_attn = (const float*)d_in[1];
    const float* w_proj = (const float*)d_in[2];
    float* out = (float*)d_out;

    const int T = 2048;
    const int B = in_sizes[0] / (T * CEMB);
    const int M = B * T;

    unsigned short* qkvh = (unsigned short*)d_ws;          // [M][3C]
    unsigned short* qkvl = qkvh + (size_t)M * C3;
    unsigned short* yh   = qkvl + (size_t)M * C3;          // [M][C]
    unsigned short* yl   = yh   + (size_t)M * CEMB;
    unsigned short* xh   = yl   + (size_t)M * CEMB;
    unsigned short* xl   = xh   + (size_t)M * CEMB;
    unsigned short* wah  = xl   + (size_t)M * CEMB;
    unsigned short* wal  = wah  + (size_t)C3 * CEMB;
    unsigned short* wph  = wal  + (size_t)C3 * CEMB;
    unsigned short* wpl  = wph  + (size_t)CEMB * CEMB;

    split_bf16_kernel<<<2048, TB, 0, stream>>>(x, xh, xl, M * CEMB / 8);
    split_bf16_kernel<<<1536, TB, 0, stream>>>(w_attn, wah, wal, C3 * CEMB / 8);
    split_bf16_kernel<<<512,  TB, 0, stream>>>(w_proj, wph, wpl, CEMB * CEMB / 8);

    gemm_split_mfma_kernel<1><<<dim3((M / 128) * (C3 / 128)), dim3(TB), 0, stream>>>(
        xh, xl, wah, wal, nullptr, qkvh, qkvl, M, C3, CEMB);

    attn_mfma_kernel<<<dim3(B * NHD * (T / 64)), dim3(TB), 0, stream>>>(
        qkvh, qkvl, yh, yl, T);

    gemm_split_mfma_kernel<0><<<dim3((M / 128) * (CEMB / 128)), dim3(TB), 0, stream>>>(
        yh, yl, wph, wpl, out, nullptr, nullptr, M, CEMB, CEMB);
}

// Round 7
// 247.273 us; speedup vs baseline: 2.6988x; 1.1266x over previous
//
#include <hip/hip_runtime.h>

// LocalGlobalCausalSelfAttention — R6 resubmit (R6 bench was an acquisition
// timeout — infra, not a kernel verdict; code unchanged for a clean A/B vs
// the R5 baseline).
// R6 changes under test: GEMM K-loop double-buffered (T3-min 2-phase: stage
// t+1 issued before compute of t, one barrier/K-step) + LDS chunk-XOR swizzle
// (linear gload_lds dest, inverse-swizzled global source, swizzled ds_read —
// rule #21). Split kernels fused into one. Attention unchanged from R5.

#define NHD   16
#define CEMB  1024
#define C3    3072
#define DH    64
#define WIN   256
#define NGLB  4
#define TB    256

typedef __attribute__((ext_vector_type(8))) short  short8v;
typedef __attribute__((ext_vector_type(4))) float  f32x4;
typedef __attribute__((ext_vector_type(8))) unsigned short ushort8v;

__device__ __forceinline__ unsigned short f2bf_rn(float f) {
    unsigned int u = __float_as_uint(f);
    u += 0x7fffu + ((u >> 16) & 1u);
    return (unsigned short)(u >> 16);
}
__device__ __forceinline__ float bf2f(unsigned short h) {
    return __uint_as_float(((unsigned int)h) << 16);
}

// ---------- fused fp32 -> (bf16 hi, bf16 lo) split for x, w_attn, w_proj ----------
__global__ __launch_bounds__(TB)
void split3_kernel(const float* __restrict__ x, const float* __restrict__ wa,
                   const float* __restrict__ wp,
                   unsigned short* __restrict__ xh, unsigned short* __restrict__ xl,
                   unsigned short* __restrict__ wah, unsigned short* __restrict__ wal,
                   unsigned short* __restrict__ wph, unsigned short* __restrict__ wpl,
                   int n8x, int n8a, int n8p) {
    const int total = n8x + n8a + n8p;
    for (int i = blockIdx.x * blockDim.x + threadIdx.x; i < total;
         i += gridDim.x * blockDim.x) {
        const float* src; unsigned short *ph, *pl; int j;
        if (i < n8x)            { src = x;  ph = xh;  pl = xl;  j = i; }
        else if (i < n8x + n8a) { src = wa; ph = wah; pl = wal; j = i - n8x; }
        else                    { src = wp; ph = wph; pl = wpl; j = i - n8x - n8a; }
        float4 v0 = ((const float4*)src)[2 * j];
        float4 v1 = ((const float4*)src)[2 * j + 1];
        float f[8] = {v0.x, v0.y, v0.z, v0.w, v1.x, v1.y, v1.z, v1.w};
        ushort8v h, l;
#pragma unroll
        for (int e = 0; e < 8; ++e) {
            unsigned short hb = f2bf_rn(f[e]);
            h[e] = hb;
            l[e] = f2bf_rn(f[e] - bf2f(hb));
        }
        *(ushort8v*)&ph[(size_t)j * 8] = h;
        *(ushort8v*)&pl[(size_t)j * 8] = l;
    }
}

// ---------- split-bf16 MFMA GEMM: C[M,N] = A[M,K] * B[N,K]^T ----------
// 128x128 tile, BK=32, 4 waves (2x2), 4x4 frags of mfma_f32_16x16x32_bf16,
// 3-term split => 48 MFMA/wave/K-step. Double-buffered LDS (2 x 4 planes x 8KB
// = 64KB): STAGE(t+1) issued before ds_read+MFMA of t; one __syncthreads
// (= vmcnt(0)+lgkmcnt(0)+barrier) per K-step.
// LDS swizzle: 16B chunk c of row r lives at chunk-slot c ^ ((r>>1)&3).
//   - gload_lds dest is linear (lane l -> row 16s+(l>>2), slot l&3), so the
//     global SOURCE chunk is pre-permuted: c_g = (l&3) ^ ((l>>3)&3)
//     (since ((16s+(l>>2))>>1)&3 == (l>>3)&3).
//   - ds_read of (row, chunk g): idx = row*32 + ((g ^ ((fr>>1)&3))<<3)
//     (row = {wr,wc}*64+m*16+fr => (row>>1)&3 == (fr>>1)&3).
//   Worst-case aliasing 2-way (free, m136) vs 4/8-way linear.
__device__ __forceinline__ void g2l16(const void* g, void* l) {
    __builtin_amdgcn_global_load_lds(
        (const __attribute__((address_space(1))) void*)g,
        (__attribute__((address_space(3))) void*)l, 16, 0, 0);
}

// OUTMODE 0: f32 C.  OUTMODE 1: hi/lo bf16 C, cols < CEMB scaled by 1/8 (Q).
template<int OUTMODE>
__global__ __launch_bounds__(TB)
void gemm_split_mfma_kernel(const unsigned short* __restrict__ Ah,
                            const unsigned short* __restrict__ Al,
                            const unsigned short* __restrict__ Bh,
                            const unsigned short* __restrict__ Bl,
                            float* __restrict__ Cf,
                            unsigned short* __restrict__ Ch,
                            unsigned short* __restrict__ Cl,
                            int M, int N, int K) {
    __shared__ unsigned short lds[2][4][128 * 32];   // dbuf x {Ah,Al,Bh,Bl}

    const int tid  = threadIdx.x;
    const int wave = tid >> 6;
    const int lane = tid & 63;
    const int nbn  = N >> 7;
    const int mb   = blockIdx.x / nbn;
    const int nb   = blockIdx.x % nbn;

    // staging: slot c in {0,1}: rows (c*4+wave)*16 + lane/4; source chunk swizzled
    const int row0 = (wave)     * 16 + (lane >> 2);
    const int row1 = (wave + 4) * 16 + (lane >> 2);
    const int koff = (((lane & 3) ^ ((lane >> 3) & 3)) << 3);   // inverse-swz source
    const size_t aoff0 = (size_t)(mb * 128 + row0) * K + koff;
    const size_t aoff1 = (size_t)(mb * 128 + row1) * K + koff;
    const size_t boff0 = (size_t)(nb * 128 + row0) * K + koff;
    const size_t boff1 = (size_t)(nb * 128 + row1) * K + koff;
    const int l0 = wave * 512;          // wave-uniform LDS bases (ushort idx)
    const int l1 = (wave + 4) * 512;

    const int wr = wave >> 1, wc = wave & 1;
    const int fr = lane & 15;
    const int g  = lane >> 4;                    // k-chunk 0..3
    const int ksel = (fr >> 1) & 3;              // read-side swizzle selector

    f32x4 acc[4][4];
#pragma unroll
    for (int m = 0; m < 4; ++m)
#pragma unroll
        for (int n = 0; n < 4; ++n) acc[m][n] = (f32x4){0.f, 0.f, 0.f, 0.f};

    auto STAGE = [&](int bi, int kt) {
        g2l16(Ah + aoff0 + kt, &lds[bi][0][l0]);
        g2l16(Ah + aoff1 + kt, &lds[bi][0][l1]);
        g2l16(Al + aoff0 + kt, &lds[bi][1][l0]);
        g2l16(Al + aoff1 + kt, &lds[bi][1][l1]);
        g2l16(Bh + boff0 + kt, &lds[bi][2][l0]);
        g2l16(Bh + boff1 + kt, &lds[bi][2][l1]);
        g2l16(Bl + boff0 + kt, &lds[bi][3][l0]);
        g2l16(Bl + boff1 + kt, &lds[bi][3][l1]);
    };

    STAGE(0, 0);
    __syncthreads();                     // drain vmcnt(0): buf0 ready
    int cur = 0;

    for (int kt = 0; kt < K; kt += 32) {
        if (kt + 32 < K) STAGE(cur ^ 1, kt + 32);   // in flight across compute

        const int co = ((g ^ ksel) << 3);           // swizzled chunk offset
        short8v ah[4], al[4], bh[4], bl[4];
#pragma unroll
        for (int m = 0; m < 4; ++m) {
            const int r = (wr * 64 + m * 16 + fr) * 32 + co;
            ah[m] = *(const short8v*)&lds[cur][0][r];
            al[m] = *(const short8v*)&lds[cur][1][r];
        }
#pragma unroll
        for (int n = 0; n < 4; ++n) {
            const int r = (wc * 64 + n * 16 + fr) * 32 + co;
            bh[n] = *(const short8v*)&lds[cur][2][r];
            bl[n] = *(const short8v*)&lds[cur][3][r];
        }
#pragma unroll
        for (int m = 0; m < 4; ++m)
#pragma unroll
            for (int n = 0; n < 4; ++n) {
                acc[m][n] = __builtin_amdgcn_mfma_f32_16x16x32_bf16(
                    ah[m], bh[n], acc[m][n], 0, 0, 0);
                acc[m][n] = __builtin_amdgcn_mfma_f32_16x16x32_bf16(
                    ah[m], bl[n], acc[m][n], 0, 0, 0);
                acc[m][n] = __builtin_amdgcn_mfma_f32_16x16x32_bf16(
                    al[m], bh[n], acc[m][n], 0, 0, 0);
            }

        __syncthreads();   // vmcnt(0)+lgkmcnt(0)+barrier: next buf staged,
        cur ^= 1;          // this buf free for overwrite next iteration
    }

    const int cr = (lane >> 4) * 4;
#pragma unroll
    for (int m = 0; m < 4; ++m)
#pragma unroll
        for (int n = 0; n < 4; ++n) {
#pragma unroll
            for (int r = 0; r < 4; ++r) {
                const int row = mb * 128 + wr * 64 + m * 16 + cr + r;
                const int col = nb * 128 + wc * 64 + n * 16 + fr;
                if constexpr (OUTMODE == 0) {
                    Cf[(size_t)row * N + col] = acc[m][n][r];
                } else {
                    float v = acc[m][n][r];
                    if (col < CEMB) v *= 0.125f;   // pre-scale Q by 1/sqrt(D)
                    unsigned short hb = f2bf_rn(v);
                    Ch[(size_t)row * N + col] = hb;
                    Cl[(size_t)row * N + col] = f2bf_rn(v - bf2f(hb));
                }
            }
        }
}

// ---------- fused attention, split-bf16 MFMA (unchanged from R5, passing) ----------
__global__ __launch_bounds__(TB)
void attn_mfma_kernel(const unsigned short* __restrict__ qkvh,
                      const unsigned short* __restrict__ qkvl,
                      unsigned short* __restrict__ yh,
                      unsigned short* __restrict__ yl, int T) {
    __shared__ unsigned short Kh[4096], Kl[4096], VTh[4096], VTl[4096],
                              Ph[4096], Pl[4096];

    const int tid = threadIdx.x;
    const int wv  = tid >> 6, ln = tid & 63;
    const int g   = ln >> 4, fr = ln & 15;
    const int nq  = T >> 6;
    const int qt  = blockIdx.x % nq;
    const int bh  = blockIdx.x / nq;
    const int h   = bh % NHD, b = bh / NHD;
    const int qs  = qt << 6;
    const size_t bT = (size_t)b * T;

    const size_t qbase = (bT + qs + wv * 16 + fr) * C3 + h * DH;
    short8v qfh[2], qfl[2];
    qfh[0] = *(const short8v*)(qkvh + qbase + g * 8);
    qfh[1] = *(const short8v*)(qkvh + qbase + 32 + g * 8);
    qfl[0] = *(const short8v*)(qkvl + qbase + g * 8);
    qfl[1] = *(const short8v*)(qkvl + qbase + 32 + g * 8);

    float mrow[4], lrow[4];
    f32x4 acc_o[4];
#pragma unroll
    for (int r = 0; r < 4; ++r) { mrow[r] = -3.0e38f; lrow[r] = 0.f; }
#pragma unroll
    for (int j = 0; j < 4; ++j) acc_o[j] = (f32x4){0.f, 0.f, 0.f, 0.f};

    int kt_first = 0;
    const int wstart = qs - (WIN - 1);
    if (wstart > 0) kt_first = wstart >> 6;
    const int has_g = (kt_first > 0) ? 1 : 0;
    const int npass = qt - kt_first + 1 + has_g;

    const int srow = tid >> 2;
    const int sc   = tid & 3;
    const int kidx0 = srow * 64 + ((sc * 8)       ^ ((srow & 7) << 3));
    const int kidx1 = srow * 64 + (((sc + 4) * 8) ^ ((srow & 7) << 3));

    short8v kh0, kh1, kl0, kl1, vh0, vh1, vl0, vl1;
    auto load_tile = [&](int k0) {
        const size_t kb = (bT + k0 + srow) * C3 + CEMB + h * DH;
        kh0 = *(const short8v*)(qkvh + kb + sc * 8);
        kh1 = *(const short8v*)(qkvh + kb + (sc + 4) * 8);
        kl0 = *(const short8v*)(qkvl + kb + sc * 8);
        kl1 = *(const short8v*)(qkvl + kb + (sc + 4) * 8);
        const size_t vb = (bT + k0 + srow) * C3 + 2 * CEMB + h * DH + sc * 16;
        vh0 = *(const short8v*)(qkvh + vb);
        vh1 = *(const short8v*)(qkvh + vb + 8);
        vl0 = *(const short8v*)(qkvl + vb);
        vl1 = *(const short8v*)(qkvl + vb + 8);
    };
    auto kt_of = [&](int p) { return (has_g && p == 0) ? 0 : (kt_first + p - has_g); };

    load_tile(kt_of(0) * 64);

    for (int pass = 0; pass < npass; ++pass) {
        const int k0 = kt_of(pass) * 64;

        __syncthreads();
        *(short8v*)&Kh[kidx0] = kh0; *(short8v*)&Kh[kidx1] = kh1;
        *(short8v*)&Kl[kidx0] = kl0; *(short8v*)&Kl[kidx1] = kl1;
#pragma unroll
        for (int e = 0; e < 8; ++e) {
            const int d1 = sc * 16 + e, d2 = sc * 16 + 8 + e;
            const int i1 = d1 * 64 + (srow ^ (((d1 ^ (d1 >> 3)) & 7) << 3));
            const int i2 = d2 * 64 + (srow ^ (((d2 ^ (d2 >> 3)) & 7) << 3));
            VTh[i1] = (unsigned short)vh0[e]; VTh[i2] = (unsigned short)vh1[e];
            VTl[i1] = (unsigned short)vl0[e]; VTl[i2] = (unsigned short)vl1[e];
        }
        __syncthreads();

        if (pass + 1 < npass) load_tile(kt_of(pass + 1) * 64);

        f32x4 sa[4];
#pragma unroll
        for (int j = 0; j < 4; ++j) sa[j] = (f32x4){0.f, 0.f, 0.f, 0.f};
#pragma unroll
        for (int kk = 0; kk < 2; ++kk) {
#pragma unroll
            for (int j = 0; j < 4; ++j) {
                const int krow = j * 16 + fr;
                const int off  = (kk * 32 + g * 8) ^ ((krow & 7) << 3);
                short8v bhf = *(const short8v*)&Kh[krow * 64 + off];
                short8v blf = *(const short8v*)&Kl[krow * 64 + off];
                sa[j] = __builtin_amdgcn_mfma_f32_16x16x32_bf16(qfh[kk], bhf, sa[j], 0, 0, 0);
                sa[j] = __builtin_amdgcn_mfma_f32_16x16x32_bf16(qfh[kk], blf, sa[j], 0, 0, 0);
                sa[j] = __builtin_amdgcn_mfma_f32_16x16x32_bf16(qfl[kk], bhf, sa[j], 0, 0, 0);
            }
        }

#pragma unroll
        for (int r = 0; r < 4; ++r) {
            const int qloc = wv * 16 + g * 4 + r;
            const int qi   = qs + qloc;
            const int wlo  = qi - (WIN - 1);
            float mx = mrow[r];
            float s[4];
#pragma unroll
            for (int j = 0; j < 4; ++j) {
                const int kj = k0 + j * 16 + fr;
                const bool valid = (kj <= qi) && ((kj >= wlo) || (kj < NGLB));
                s[j] = valid ? sa[j][r] : -3.0e38f;
                mx = fmaxf(mx, s[j]);
            }
#pragma unroll
            for (int off = 1; off < 16; off <<= 1)
                mx = fmaxf(mx, __shfl_xor(mx, off, 64));
            const float alpha = __expf(mrow[r] - mx);
            float rsum = 0.f;
            unsigned short phv[4], plv[4];
#pragma unroll
            for (int j = 0; j < 4; ++j) {
                const float p = (s[j] > -1.0e38f) ? __expf(s[j] - mx) : 0.f;
                rsum += p;
                const unsigned short hb = f2bf_rn(p);
                phv[j] = hb; plv[j] = f2bf_rn(p - bf2f(hb));
            }
#pragma unroll
            for (int off = 1; off < 16; off <<= 1)
                rsum += __shfl_xor(rsum, off, 64);
            lrow[r] = lrow[r] * alpha + rsum;
            mrow[r] = mx;
#pragma unroll
            for (int j = 0; j < 4; ++j) {
                acc_o[j][r] *= alpha;
                const int key = j * 16 + fr;
                const int idx = qloc * 64 + (key ^ ((qloc & 7) << 3));
                Ph[idx] = phv[j]; Pl[idx] = plv[j];
            }
        }

#pragma unroll
        for (int kk = 0; kk < 2; ++kk) {
            const int qloc = wv * 16 + fr;
            const int poff = (kk * 32 + g * 8) ^ ((qloc & 7) << 3);
            short8v pah = *(const short8v*)&Ph[qloc * 64 + poff];
            short8v pal = *(const short8v*)&Pl[qloc * 64 + poff];
#pragma unroll
            for (int j = 0; j < 4; ++j) {
                const int d   = j * 16 + fr;
                const int voff = (kk * 32 + g * 8) ^ (((d ^ (d >> 3)) & 7) << 3);
                short8v vfh = *(const short8v*)&VTh[d * 64 + voff];
                short8v vfl = *(const short8v*)&VTl[d * 64 + voff];
                acc_o[j] = __builtin_amdgcn_mfma_f32_16x16x32_bf16(pah, vfh, acc_o[j], 0, 0, 0);
                acc_o[j] = __builtin_amdgcn_mfma_f32_16x16x32_bf16(pah, vfl, acc_o[j], 0, 0, 0);
                acc_o[j] = __builtin_amdgcn_mfma_f32_16x16x32_bf16(pal, vfh, acc_o[j], 0, 0, 0);
            }
        }
    }

    float inv[4];
#pragma unroll
    for (int r = 0; r < 4; ++r) inv[r] = 1.0f / lrow[r];
#pragma unroll
    for (int j = 0; j < 4; ++j)
#pragma unroll
        for (int r = 0; r < 4; ++r) {
            const float o = acc_o[j][r] * inv[r];
            const size_t yi = (bT + qs + wv * 16 + g * 4 + r) * (size_t)CEMB
                            + h * DH + j * 16 + fr;
            const unsigned short hb = f2bf_rn(o);
            yh[yi] = hb; yl[yi] = f2bf_rn(o - bf2f(hb));
        }
}

// ===================== launcher =====================
extern "C" void kernel_launch(void* const* d_in, const int* in_sizes, int n_in,
                              void* d_out, int out_size, void* d_ws, size_t ws_size,
                              hipStream_t stream) {
    const float* x      = (const float*)d_in[0];
    const float* w_attn = (const float*)d_in[1];
    const float* w_proj = (const float*)d_in[2];
    float* out = (float*)d_out;

    const int T = 2048;
    const int B = in_sizes[0] / (T * CEMB);
    const int M = B * T;

    unsigned short* qkvh = (unsigned short*)d_ws;          // [M][3C]
    unsigned short* qkvl = qkvh + (size_t)M * C3;
    unsigned short* yh   = qkvl + (size_t)M * C3;          // [M][C]
    unsigned short* yl   = yh   + (size_t)M * CEMB;
    unsigned short* xh   = yl   + (size_t)M * CEMB;
    unsigned short* xl   = xh   + (size_t)M * CEMB;
    unsigned short* wah  = xl   + (size_t)M * CEMB;
    unsigned short* wal  = wah  + (size_t)C3 * CEMB;
    unsigned short* wph  = wal  + (size_t)C3 * CEMB;
    unsigned short* wpl  = wph  + (size_t)CEMB * CEMB;

    const int n8x = M * CEMB / 8;
    const int n8a = C3 * CEMB / 8;
    const int n8p = CEMB * CEMB / 8;
    split3_kernel<<<2048, TB, 0, stream>>>(x, w_attn, w_proj,
                                           xh, xl, wah, wal, wph, wpl,
                                           n8x, n8a, n8p);

    gemm_split_mfma_kernel<1><<<dim3((M / 128) * (C3 / 128)), dim3(TB), 0, stream>>>(
        xh, xl, wah, wal, nullptr, qkvh, qkvl, M, C3, CEMB);

    attn_mfma_kernel<<<dim3(B * NHD * (T / 64)), dim3(TB), 0, stream>>>(
        qkvh, qkvl, yh, yl, T);

    gemm_split_mfma_kernel<0><<<dim3((M / 128) * (CEMB / 128)), dim3(TB), 0, stream>>>(
        yh, yl, wph, wpl, out, nullptr, nullptr, M, CEMB, CEMB);
}